// Round 15
// baseline (151.298 us; speedup 1.0000x reference)
//
#include <hip/hip_runtime.h>
#include <cmath>
#include <cstdint>

#define NB 32
#define NP 24564
#define NC 81
#define NEG_POS 3

static constexpr size_t MINED_ELEMS = (size_t)NB * NP;             // 786,048
static constexpr size_t MINED_BYTES = MINED_ELEMS * sizeof(float); // 3,144,192

#define NTILES4 ((int)(MINED_ELEMS / 4))   // 196,512 = 8188 * 24 exactly
#define MAIN_BLOCKS 2047                   // 4 waves each -> 8188 waves
#define TOTAL_WAVES (MAIN_BLOCKS * 4)
#define KITERS 12                          // x2 (A/B) = 24 tiles per wave

// ws layout:
//   [0, MINED_BYTES)            float mined[NB*NP] (sign bit = positive row, |v| = ce)
//   [MINED_BYTES, +512)         float partial[NB][4]  {loc, ce_pos, neg_sum, pad}
//   [MINED_BYTES+512, +4*NB)    int   num_pos[NB]

__device__ __forceinline__ float wave_reduce_sum(float v) {
#pragma unroll
  for (int off = 32; off > 0; off >>= 1) v += __shfl_down(v, off, 64);
  return v;
}

__device__ __forceinline__ float smooth_l1_4(float4 a, float4 t) {
  float acc = 0.f, d, ax;
  d = a.x - t.x; ax = fabsf(d); acc += (ax < 1.f) ? 0.5f * d * d : ax - 0.5f;
  d = a.y - t.y; ax = fabsf(d); acc += (ax < 1.f) ? 0.5f * d * d : ax - 0.5f;
  d = a.z - t.z; ax = fabsf(d); acc += (ax < 1.f) ? 0.5f * d * d : ax - 0.5f;
  d = a.w - t.w; ax = fabsf(d); acc += (ax < 1.f) ? 0.5f * d * d : ax - 0.5f;
  return acc;
}

// Branch-free CE kernel, fully pipelined: depth-2 data prefetch (A/B register
// sets) AND targets prefetched one tile ahead -> every wait in the loop is a
// rolling nonzero vmcnt (never a drain; the mined store ack never blocks).
__global__ __launch_bounds__(256, 8) void mb_main(
    const float* __restrict__ conf_data, const int* __restrict__ conf_targets,
    float* __restrict__ mined) {
  __shared__ float lds[4][332];

  const int tid  = (int)threadIdx.x;
  const int wid  = tid >> 6, lane = tid & 63;
  const int r    = lane >> 4, il = lane & 15;
  float* __restrict__ L = lds[wid];

  const int l17   = (lane < 17) ? lane : 16;
  const int ldst1 = (lane < 17) ? (256 + 4 * l17) : 328;

#define LOAD_DATA(c0, c1, t)                                            \
  do {                                                                  \
    const float4* __restrict__ _s =                                     \
        reinterpret_cast<const float4*>(conf_data) + (size_t)(t) * 81;  \
    (c0) = _s[lane];                                                    \
    (c1) = _s[64 + l17];                                                \
  } while (0)

#define STAGE(c0, c1)                                     \
  do {                                                    \
    *reinterpret_cast<float4*>(&L[4 * lane]) = (c0);      \
    *reinterpret_cast<float4*>(&L[ldst1]) = (c1);         \
  } while (0)

#define COMPUTE(t, tg)                                                        \
  do {                                                                        \
    const int tgt = (r == 0) ? (tg).x : (r == 1) ? (tg).y                     \
                  : (r == 2) ? (tg).z : (tg).w;                               \
    const int rb = 81 * r;                                                    \
    float e = __expf(L[rb + il]) + __expf(L[rb + il + 16]) +                  \
              __expf(L[rb + il + 32]) + __expf(L[rb + il + 48]) +             \
              __expf(L[rb + il + 64]);                                        \
    if (il == 0) e += __expf(L[rb + 80]);                                     \
    e += __shfl_xor(e, 1, 64);                                                \
    e += __shfl_xor(e, 2, 64);                                                \
    e += __shfl_xor(e, 4, 64);                                                \
    e += __shfl_xor(e, 8, 64);                                                \
    const float tv = L[rb + tgt];                                             \
    const float ce = __logf(e) - tv;                                          \
    const float val = (tgt > 0) ? -ce : ce;                                   \
    mined[(t) * 4 + r] = val;                                                 \
  } while (0)

  int tile = (int)blockIdx.x * 4 + wid;
  float4 a0, a1, b0, b1;
  int4 tgA, tgB, tgN;

  LOAD_DATA(a0, a1, tile);
  tgA = *reinterpret_cast<const int4*>(conf_targets + (size_t)tile * 4);
  {
    const int tB = tile + TOTAL_WAVES;   // always < NTILES4 (8188*24 layout)
    LOAD_DATA(b0, b1, tB);
    tgB = *reinterpret_cast<const int4*>(conf_targets + (size_t)tB * 4);
  }

#pragma unroll 1
  for (int k = 0; k < KITERS; ++k) {
    // ---- body A ----
    STAGE(a0, a1);
    {
      int tn = tile + 2 * TOTAL_WAVES;
      tn = (tn < NTILES4) ? tn : tile;
      LOAD_DATA(a0, a1, tn);
      tgN = *reinterpret_cast<const int4*>(conf_targets + (size_t)tn * 4);
    }
    __builtin_amdgcn_sched_barrier(0);
    COMPUTE(tile, tgA);
    tgA = tgN;
    tile += TOTAL_WAVES;

    // ---- body B ----
    STAGE(b0, b1);
    {
      int tn = tile + 2 * TOTAL_WAVES;
      tn = (tn < NTILES4) ? tn : tile;
      LOAD_DATA(b0, b1, tn);
      tgN = *reinterpret_cast<const int4*>(conf_targets + (size_t)tn * 4);
    }
    __builtin_amdgcn_sched_barrier(0);
    COMPUTE(tile, tgB);
    tgB = tgN;
    tile += TOTAL_WAVES;
  }
#undef LOAD_DATA
#undef STAGE
#undef COMPUTE
}

// One block per batch row. Pass 1 fuses the positives prepass with the first
// radix histogram; every pass tracks per-bin float sums so the strictly-
// greater sum accumulates from suffix sums (no final sweep). 4 sweeps total.
__global__ __launch_bounds__(1024) void mb_select(
    const float* __restrict__ mined, const float* __restrict__ loc_data,
    const float* __restrict__ loc_targets, float* __restrict__ partial,
    int* __restrict__ num_pos) {
  const int b = blockIdx.x;
  const float* __restrict__ row = mined + (size_t)b * NP;
  const int tid = threadIdx.x;
  const int wid = tid >> 6;
  const int lane = tid & 63;

  __shared__ int   hist[16][256];
  __shared__ float fsum[16][256];
  __shared__ int   total[256];
  __shared__ float ftotal[256];
  __shared__ int   suffix[256];
  __shared__ float fsuffix[256];
  __shared__ float redf[3][16];
  __shared__ unsigned s_prefix;
  __shared__ int s_k;
  __shared__ float s_gsum, s_cp, s_lv;

  if (tid == 0) { s_prefix = 0u; s_gsum = 0.f; }

  // ================= pass 1 (shift 24) + fused positives prepass ==========
  for (int i = tid; i < 16 * 256; i += 1024) { ((int*)hist)[i] = 0; ((float*)fsum)[i] = 0.f; }
  __syncthreads();

  {
    float np = 0.f, cp = 0.f, lv = 0.f;
    for (int q = tid; q < NP / 4; q += 1024) {
      const float4 v = reinterpret_cast<const float4*>(row)[q];
      const float vv[4] = {v.x, v.y, v.z, v.w};
#pragma unroll
      for (int j = 0; j < 4; ++j) {
        unsigned u = __float_as_uint(vv[j]);
        if (u >> 31) {
          np += 1.f;
          cp += -vv[j];
          const size_t flat = (size_t)b * NP + 4 * q + j;
          lv += smooth_l1_4(
              *reinterpret_cast<const float4*>(loc_data + flat * 4),
              *reinterpret_cast<const float4*>(loc_targets + flat * 4));
          u = 0u;
        }
        atomicAdd(&hist[wid][u >> 24], 1);
        atomicAdd(&fsum[wid][u >> 24], __uint_as_float(u));
      }
    }
    float wnp = wave_reduce_sum(np);
    float wcp = wave_reduce_sum(cp);
    float wlv = wave_reduce_sum(lv);
    if (lane == 0) { redf[0][wid] = wnp; redf[1][wid] = wcp; redf[2][wid] = wlv; }
  }
  __syncthreads();
  if (tid == 0) {
    float tnp = 0.f, tcp = 0.f, tlv = 0.f;
#pragma unroll
    for (int i = 0; i < 16; ++i) { tnp += redf[0][i]; tcp += redf[1][i]; tlv += redf[2][i]; }
    const int npi = (int)tnp;
    num_pos[b] = npi;
    s_cp = tcp; s_lv = tlv;
    int k = NEG_POS * npi;
    if (k > NP - 1) k = NP - 1;
    s_k = k;
  }
  __syncthreads();

  // shared epilogue for each pass: totals -> suffix scans -> choose bin
#define PASS_EPILOGUE(SHIFT)                                                  \
  do {                                                                        \
    if (tid < 256) {                                                          \
      int t = 0; float f = 0.f;                                               \
      _Pragma("unroll")                                                       \
      for (int w = 0; w < 16; ++w) { t += hist[w][tid]; f += fsum[w][tid]; }  \
      total[tid] = t; ftotal[tid] = f;                                        \
    }                                                                         \
    __syncthreads();                                                          \
    if (wid == 0) {                                                           \
      int t3 = total[4 * lane + 3], t2 = total[4 * lane + 2];                 \
      int t1 = total[4 * lane + 1], t0 = total[4 * lane + 0];                 \
      float f3 = ftotal[4 * lane + 3], f2 = ftotal[4 * lane + 2];             \
      float f1 = ftotal[4 * lane + 1], f0 = ftotal[4 * lane + 0];             \
      const int is3 = t3, is2 = t2 + is3, is1 = t1 + is2, is0 = t0 + is1;     \
      const float fs3 = f3, fs2 = f2 + fs3, fs1 = f1 + fs2, fs0 = f0 + fs1;   \
      int ia = is0; float fa = fs0;                                           \
      _Pragma("unroll")                                                       \
      for (int off = 1; off < 64; off <<= 1) {                                \
        const int io = __shfl_down(ia, off, 64);                              \
        const float fo = __shfl_down(fa, off, 64);                            \
        if (lane + off < 64) { ia += io; fa += fo; }                          \
      }                                                                       \
      const int iex = ia - is0; const float fex = fa - fs0;                   \
      suffix[4 * lane + 0] = is0 + iex; fsuffix[4 * lane + 0] = fs0 + fex;    \
      suffix[4 * lane + 1] = is1 + iex; fsuffix[4 * lane + 1] = fs1 + fex;    \
      suffix[4 * lane + 2] = is2 + iex; fsuffix[4 * lane + 2] = fs2 + fex;    \
      suffix[4 * lane + 3] = is3 + iex; fsuffix[4 * lane + 3] = fs3 + fex;    \
    }                                                                         \
    __syncthreads();                                                          \
    if (tid < 256) {                                                          \
      const int kcur = s_k;                                                   \
      const int cs = suffix[tid] - total[tid];                                \
      if (kcur >= cs && kcur < cs + total[tid]) {                             \
        s_prefix |= ((unsigned)tid << (SHIFT));                               \
        s_k = kcur - cs;                                                      \
        s_gsum += fsuffix[tid] - ftotal[tid];                                 \
      }                                                                       \
    }                                                                         \
    __syncthreads();                                                          \
  } while (0)

  PASS_EPILOGUE(24);

  // ================= passes 2..4 (shift 16, 8, 0) =========================
  for (int shift = 16; shift >= 0; shift -= 8) {
    for (int i = tid; i < 16 * 256; i += 1024) { ((int*)hist)[i] = 0; ((float*)fsum)[i] = 0.f; }
    __syncthreads();
    const unsigned mask = 0xFFFFFFFFu << (shift + 8);
    const unsigned pfx = s_prefix;

    for (int q = tid; q < NP / 4; q += 1024) {
      const float4 v = reinterpret_cast<const float4*>(row)[q];
      unsigned u;
      u = __float_as_uint(v.x); u = (u >> 31) ? 0u : u;
      if ((u & mask) == pfx) { atomicAdd(&hist[wid][(u >> shift) & 255], 1); atomicAdd(&fsum[wid][(u >> shift) & 255], __uint_as_float(u)); }
      u = __float_as_uint(v.y); u = (u >> 31) ? 0u : u;
      if ((u & mask) == pfx) { atomicAdd(&hist[wid][(u >> shift) & 255], 1); atomicAdd(&fsum[wid][(u >> shift) & 255], __uint_as_float(u)); }
      u = __float_as_uint(v.z); u = (u >> 31) ? 0u : u;
      if ((u & mask) == pfx) { atomicAdd(&hist[wid][(u >> shift) & 255], 1); atomicAdd(&fsum[wid][(u >> shift) & 255], __uint_as_float(u)); }
      u = __float_as_uint(v.w); u = (u >> 31) ? 0u : u;
      if ((u & mask) == pfx) { atomicAdd(&hist[wid][(u >> shift) & 255], 1); atomicAdd(&fsum[wid][(u >> shift) & 255], __uint_as_float(u)); }
    }
    __syncthreads();

    if (shift == 16) PASS_EPILOGUE(16);
    else if (shift == 8) PASS_EPILOGUE(8);
    else PASS_EPILOGUE(0);
  }
#undef PASS_EPILOGUE

  if (tid == 0) {
    partial[b * 4 + 0] = s_lv;
    partial[b * 4 + 1] = s_cp;
    partial[b * 4 + 2] = s_gsum;
  }
}

__global__ void mb_finalize(const float* __restrict__ partial,
                            const int* __restrict__ num_pos,
                            float* __restrict__ out) {
  if (threadIdx.x == 0) {
    double s = 0.0;
    int tot = 0;
#pragma unroll
    for (int i = 0; i < NB; ++i) {
      s += (double)partial[i * 4 + 0] + (double)partial[i * 4 + 1] +
           (double)partial[i * 4 + 2];
      tot += num_pos[i];
    }
    const double n = (double)(tot > 0 ? tot : 1);
    out[0] = (float)(s / n);
  }
}

extern "C" void kernel_launch(void* const* d_in, const int* in_sizes, int n_in,
                              void* d_out, int out_size, void* d_ws, size_t ws_size,
                              hipStream_t stream) {
  const float* loc_data     = (const float*)d_in[0];
  const float* conf_data    = (const float*)d_in[1];
  const float* loc_targets  = (const float*)d_in[2];
  const int*   conf_targets = (const int*)d_in[3];
  float* out = (float*)d_out;

  float* mined   = (float*)d_ws;
  float* partial = (float*)((char*)d_ws + MINED_BYTES);
  int*   num_pos = (int*)((char*)d_ws + MINED_BYTES + 512);

  mb_main<<<MAIN_BLOCKS, 256, 0, stream>>>(conf_data, conf_targets, mined);

  mb_select<<<NB, 1024, 0, stream>>>(mined, loc_data, loc_targets, partial, num_pos);

  mb_finalize<<<1, 64, 0, stream>>>(partial, num_pos, out);
}

// Round 16
// 99.464 us; speedup vs baseline: 1.5211x; 1.5211x over previous
//
#include <hip/hip_runtime.h>
#include <cmath>
#include <cstdint>

#define NB 32
#define NP 24564
#define NC 81
#define NEG_POS 3

static constexpr size_t MINED_ELEMS = (size_t)NB * NP;             // 786,048
static constexpr size_t MINED_BYTES = MINED_ELEMS * sizeof(float); // 3,144,192

#define NTILES4 ((int)(MINED_ELEMS / 4))   // 196,512 = 8188 * 24 exactly
#define MAIN_BLOCKS 2047                   // 4 waves each -> 8188 waves
#define TOTAL_WAVES (MAIN_BLOCKS * 4)
#define ITERS 24

// ws layout:
//   [0, MINED_BYTES)                    float mined[NB*NP]  (sign bit = positive row, |v| = ce)
//   [MINED_BYTES, +24)                  double acc[3]  {loc_loss, ce_pos_sum, neg_sum}
//   [MINED_BYTES+24, +24+4*NB)          int   num_pos[NB]

__device__ __forceinline__ float wave_reduce_sum(float v) {
#pragma unroll
  for (int off = 32; off > 0; off >>= 1) v += __shfl_down(v, off, 64);
  return v;
}

__device__ __forceinline__ float smooth_l1_4(float4 a, float4 t) {
  float acc = 0.f, d, ax;
  d = a.x - t.x; ax = fabsf(d); acc += (ax < 1.f) ? 0.5f * d * d : ax - 0.5f;
  d = a.y - t.y; ax = fabsf(d); acc += (ax < 1.f) ? 0.5f * d * d : ax - 0.5f;
  d = a.z - t.z; ax = fabsf(d); acc += (ax < 1.f) ? 0.5f * d * d : ax - 0.5f;
  d = a.w - t.w; ax = fabsf(d); acc += (ax < 1.f) ? 0.5f * d * d : ax - 0.5f;
  return acc;
}

__global__ void mb_init(double* __restrict__ acc, int* __restrict__ num_pos) {
  int t = threadIdx.x;
  if (t < 3) acc[t] = 0.0;
  if (t < NB) num_pos[t] = 0;
}

// Branch-free CE kernel (R14 structure) with ONE change: targets ping-pong
// (tgCur consumed this iter was loaded last iter) so COMPUTE waits on nothing
// issued this iteration -- the data prefetch stays in flight through compute.
__global__ __launch_bounds__(256, 8) void mb_main(
    const float* __restrict__ conf_data, const int* __restrict__ conf_targets,
    float* __restrict__ mined) {
  __shared__ float lds[4][332];   // 324 data + dump slot

  const int tid  = (int)threadIdx.x;
  const int wid  = tid >> 6, lane = tid & 63;
  const int r    = lane >> 4, il = lane & 15;
  float* __restrict__ L = lds[wid];

  const int l17   = (lane < 17) ? lane : 16;              // clamped src index
  const int ldst1 = (lane < 17) ? (256 + 4 * l17) : 328;  // dump for lanes>=17

  int tile = (int)blockIdx.x * 4 + wid;
  float4 c0, c1;
  int4 tgCur, tgN;
  {
    const float4* __restrict__ src =
        reinterpret_cast<const float4*>(conf_data) + (size_t)tile * 81;
    c0 = src[lane];
    c1 = src[64 + l17];
    tgCur = *reinterpret_cast<const int4*>(conf_targets + (size_t)tile * 4);
  }

#pragma unroll 1
  for (int k = 0; k < ITERS; ++k) {
    // stage current tile (waits only on c0/c1's loads from LAST iteration)
    *reinterpret_cast<float4*>(&L[4 * lane]) = c0;
    *reinterpret_cast<float4*>(&L[ldst1]) = c1;

    // prefetch next tile's data AND targets (all consumed next iteration)
    {
      int nt = tile + TOTAL_WAVES;
      nt = (nt < NTILES4) ? nt : tile;
      const float4* __restrict__ src =
          reinterpret_cast<const float4*>(conf_data) + (size_t)nt * 81;
      c0 = src[lane];
      c1 = src[64 + l17];
      tgN = *reinterpret_cast<const int4*>(conf_targets + (size_t)nt * 4);
    }
    __builtin_amdgcn_sched_barrier(0);   // keep prefetch above compute

    const int tgt = (r == 0) ? tgCur.x : (r == 1) ? tgCur.y
                  : (r == 2) ? tgCur.z : tgCur.w;

    const int rb = 81 * r;
    float e = __expf(L[rb + il]) + __expf(L[rb + il + 16]) +
              __expf(L[rb + il + 32]) + __expf(L[rb + il + 48]) +
              __expf(L[rb + il + 64]);
    if (il == 0) e += __expf(L[rb + 80]);   // VALU-only divergence: harmless
    e += __shfl_xor(e, 1, 64);
    e += __shfl_xor(e, 2, 64);
    e += __shfl_xor(e, 4, 64);
    e += __shfl_xor(e, 8, 64);

    const float tv = L[rb + tgt];           // LDS gather (16-lane broadcast)
    const float ce = __logf(e) - tv;        // unstabilized LSE safe: |x| < ~6
    const float val = (tgt > 0) ? -ce : ce; // sign bit marks positive rows
    mined[tile * 4 + r] = val;              // unconditional, 16-lane redundant

    tgCur = tgN;
    tile += TOTAL_WAVES;
  }
}

// One block per batch row (R14 version, unchanged). Pre-pass: positives ->
// num_pos, ce_pos, loc smooth-L1; then radix-select (sign-set masked to 0.0)
// and strict-greater negative sum.
__global__ __launch_bounds__(1024) void mb_select(
    const float* __restrict__ mined, const float* __restrict__ loc_data,
    const float* __restrict__ loc_targets, double* __restrict__ acc,
    int* __restrict__ num_pos) {
  const int b = blockIdx.x;
  const float* __restrict__ row = mined + (size_t)b * NP;
  const int tid = threadIdx.x;
  const int wid = tid >> 6;
  const int lane = tid & 63;

  __shared__ int hist[16][256];
  __shared__ int total[256];
  __shared__ int suffix[256];
  __shared__ unsigned s_prefix;
  __shared__ int s_k;

  // ---- pre-pass: positives ----
  {
    int np = 0;
    float cp = 0.f, lv = 0.f;
    for (int q = tid; q < NP / 4; q += 1024) {
      const float4 v = reinterpret_cast<const float4*>(row)[q];
      const float vv[4] = {v.x, v.y, v.z, v.w};
#pragma unroll
      for (int j = 0; j < 4; ++j) {
        if (__float_as_uint(vv[j]) >> 31) {
          np++;
          cp += -vv[j];
          const size_t flat = (size_t)b * NP + 4 * q + j;
          lv += smooth_l1_4(
              *reinterpret_cast<const float4*>(loc_data + flat * 4),
              *reinterpret_cast<const float4*>(loc_targets + flat * 4));
        }
      }
    }
    __shared__ float rednp[16], redcp[16], redlv[16];
    float wnp = wave_reduce_sum((float)np);
    float wcp = wave_reduce_sum(cp);
    float wlv = wave_reduce_sum(lv);
    if (lane == 0) { rednp[wid] = wnp; redcp[wid] = wcp; redlv[wid] = wlv; }
    __syncthreads();
    if (tid == 0) {
      float tnp = 0.f, tcp = 0.f, tlv = 0.f;
#pragma unroll
      for (int i = 0; i < 16; ++i) { tnp += rednp[i]; tcp += redcp[i]; tlv += redlv[i]; }
      const int npi = (int)tnp;
      num_pos[b] = npi;
      if (tcp != 0.f) atomicAdd(&acc[1], (double)tcp);
      if (tlv != 0.f) atomicAdd(&acc[0], (double)tlv);
      int k = NEG_POS * npi;
      if (k > NP - 1) k = NP - 1;
      s_k = k;
      s_prefix = 0u;
    }
    __syncthreads();
  }

  // ---- radix select over masked values (sign-set -> 0.0) ----
  for (int shift = 24; shift >= 0; shift -= 8) {
    for (int i = tid; i < 16 * 256; i += 1024) ((int*)hist)[i] = 0;
    __syncthreads();
    const unsigned mask = (shift == 24) ? 0u : (0xFFFFFFFFu << (shift + 8));
    const unsigned pfx = s_prefix;
    const int kcur = s_k;

    for (int q = tid; q < NP / 4; q += 1024) {
      const float4 v = reinterpret_cast<const float4*>(row)[q];
      unsigned u;
      u = __float_as_uint(v.x); u = (u >> 31) ? 0u : u; if ((u & mask) == pfx) atomicAdd(&hist[wid][(u >> shift) & 255], 1);
      u = __float_as_uint(v.y); u = (u >> 31) ? 0u : u; if ((u & mask) == pfx) atomicAdd(&hist[wid][(u >> shift) & 255], 1);
      u = __float_as_uint(v.z); u = (u >> 31) ? 0u : u; if ((u & mask) == pfx) atomicAdd(&hist[wid][(u >> shift) & 255], 1);
      u = __float_as_uint(v.w); u = (u >> 31) ? 0u : u; if ((u & mask) == pfx) atomicAdd(&hist[wid][(u >> shift) & 255], 1);
    }
    __syncthreads();

    if (tid < 256) {
      int t = 0;
#pragma unroll
      for (int w = 0; w < 16; ++w) t += hist[w][tid];
      total[tid] = t;
    }
    __syncthreads();

    if (wid == 0) {
      const int t0_ = total[4 * lane + 0];
      const int t1_ = total[4 * lane + 1];
      const int t2_ = total[4 * lane + 2];
      const int t3_ = total[4 * lane + 3];
      const int s3 = t3_;
      const int s2 = t2_ + s3;
      const int s1 = t1_ + s2;
      const int s0 = t0_ + s1;
      int acc_ = s0;
#pragma unroll
      for (int off = 1; off < 64; off <<= 1) {
        const int o = __shfl_down(acc_, off, 64);
        if (lane + off < 64) acc_ += o;
      }
      const int excl = acc_ - s0;
      suffix[4 * lane + 0] = s0 + excl;
      suffix[4 * lane + 1] = s1 + excl;
      suffix[4 * lane + 2] = s2 + excl;
      suffix[4 * lane + 3] = s3 + excl;
    }
    __syncthreads();

    if (tid < 256) {
      const int cs = suffix[tid] - total[tid];
      if (kcur >= cs && kcur < cs + total[tid]) {
        s_prefix = pfx | ((unsigned)tid << shift);
        s_k = kcur - cs;
      }
    }
    __syncthreads();
  }

  const unsigned vbits = s_prefix;   // pivot bit pattern (masked domain)
  float sum = 0.f;
  for (int q = tid; q < NP / 4; q += 1024) {
    const float4 v = reinterpret_cast<const float4*>(row)[q];
    unsigned u;
    u = __float_as_uint(v.x); u = (u >> 31) ? 0u : u; if (u > vbits) sum += v.x;
    u = __float_as_uint(v.y); u = (u >> 31) ? 0u : u; if (u > vbits) sum += v.y;
    u = __float_as_uint(v.z); u = (u >> 31) ? 0u : u; if (u > vbits) sum += v.z;
    u = __float_as_uint(v.w); u = (u >> 31) ? 0u : u; if (u > vbits) sum += v.w;
  }

  __shared__ float wsum[16];
  float w = wave_reduce_sum(sum);
  if (lane == 0) wsum[wid] = w;
  __syncthreads();
  if (tid == 0) {
    float t = 0.f;
#pragma unroll
    for (int i = 0; i < 16; ++i) t += wsum[i];
    atomicAdd(&acc[2], (double)t);
  }
}

__global__ void mb_finalize(const double* __restrict__ acc,
                            const int* __restrict__ num_pos,
                            float* __restrict__ out) {
  if (threadIdx.x == 0) {
    int tot = 0;
#pragma unroll
    for (int i = 0; i < NB; ++i) tot += num_pos[i];
    const double n = (double)(tot > 0 ? tot : 1);
    out[0] = (float)((acc[0] + acc[1] + acc[2]) / n);
  }
}

extern "C" void kernel_launch(void* const* d_in, const int* in_sizes, int n_in,
                              void* d_out, int out_size, void* d_ws, size_t ws_size,
                              hipStream_t stream) {
  const float* loc_data     = (const float*)d_in[0];
  const float* conf_data    = (const float*)d_in[1];
  const float* loc_targets  = (const float*)d_in[2];
  const int*   conf_targets = (const int*)d_in[3];
  float* out = (float*)d_out;

  float*  mined   = (float*)d_ws;
  double* acc     = (double*)((char*)d_ws + MINED_BYTES);
  int*    num_pos = (int*)((char*)d_ws + MINED_BYTES + 3 * sizeof(double));

  mb_init<<<1, 64, 0, stream>>>(acc, num_pos);

  mb_main<<<MAIN_BLOCKS, 256, 0, stream>>>(conf_data, conf_targets, mined);

  mb_select<<<NB, 1024, 0, stream>>>(mined, loc_data, loc_targets, acc, num_pos);

  mb_finalize<<<1, 64, 0, stream>>>(acc, num_pos, out);
}

// Round 17
// 95.793 us; speedup vs baseline: 1.5794x; 1.0383x over previous
//
#include <hip/hip_runtime.h>
#include <cmath>
#include <cstdint>

#define NB 32
#define NP 24564
#define NC 81
#define NEG_POS 3

static constexpr size_t MINED_ELEMS = (size_t)NB * NP;             // 786,048
static constexpr size_t MINED_BYTES = MINED_ELEMS * sizeof(float); // 3,144,192

#define NTILES4 ((int)(MINED_ELEMS / 4))   // 196,512 = 8188 * 24 exactly
#define MAIN_BLOCKS 2047                   // 4 waves each -> 8188 waves
#define TOTAL_WAVES (MAIN_BLOCKS * 4)
#define KITERS 12                          // x2 bodies = 24 tiles per wave

// ws layout:
//   [0, MINED_BYTES)            float mined[NB*NP] (sign bit = positive row, |v| = ce)
//   [MINED_BYTES, +512)         float partial[NB][4] {loc, ce_pos, neg_sum, pad}
//   [MINED_BYTES+512, +4*NB)    int   num_pos[NB]

__device__ __forceinline__ float wave_reduce_sum(float v) {
#pragma unroll
  for (int off = 32; off > 0; off >>= 1) v += __shfl_down(v, off, 64);
  return v;
}

__device__ __forceinline__ float smooth_l1_4(float4 a, float4 t) {
  float acc = 0.f, d, ax;
  d = a.x - t.x; ax = fabsf(d); acc += (ax < 1.f) ? 0.5f * d * d : ax - 0.5f;
  d = a.y - t.y; ax = fabsf(d); acc += (ax < 1.f) ? 0.5f * d * d : ax - 0.5f;
  d = a.z - t.z; ax = fabsf(d); acc += (ax < 1.f) ? 0.5f * d * d : ax - 0.5f;
  d = a.w - t.w; ax = fabsf(d); acc += (ax < 1.f) ? 0.5f * d * d : ax - 0.5f;
  return acc;
}

// Branch-free CE kernel, depth-2 pipeline: STAGE waits on loads issued TWO
// iterations ago (rolling vmcnt(~5), ~full HBM latency coverage); targets
// rotate 3-deep so COMPUTE never waits on anything issued this iteration.
__global__ __launch_bounds__(256, 8) void mb_main(
    const float* __restrict__ conf_data, const int* __restrict__ conf_targets,
    float* __restrict__ mined) {
  __shared__ float lds[4][332];   // 324 data + dump slot

  const int tid  = (int)threadIdx.x;
  const int wid  = tid >> 6, lane = tid & 63;
  const int r    = lane >> 4, il = lane & 15;
  float* __restrict__ L = lds[wid];

  const int l17   = (lane < 17) ? lane : 16;              // clamped src index
  const int ldst1 = (lane < 17) ? (256 + 4 * l17) : 328;  // dump for lanes>=17

#define LOAD_DATA(c0, c1, t)                                            \
  do {                                                                  \
    const float4* __restrict__ _s =                                     \
        reinterpret_cast<const float4*>(conf_data) + (size_t)(t) * 81;  \
    (c0) = _s[lane];                                                    \
    (c1) = _s[64 + l17];                                                \
  } while (0)

#define STAGE(c0, c1)                                  \
  do {                                                 \
    *reinterpret_cast<float4*>(&L[4 * lane]) = (c0);   \
    *reinterpret_cast<float4*>(&L[ldst1]) = (c1);      \
  } while (0)

#define COMPUTE(t, tg)                                                  \
  do {                                                                  \
    const int tgt = (r == 0) ? (tg).x : (r == 1) ? (tg).y               \
                  : (r == 2) ? (tg).z : (tg).w;                         \
    const int rb = 81 * r;                                              \
    float e = __expf(L[rb + il]) + __expf(L[rb + il + 16]) +            \
              __expf(L[rb + il + 32]) + __expf(L[rb + il + 48]) +       \
              __expf(L[rb + il + 64]);                                  \
    if (il == 0) e += __expf(L[rb + 80]);                               \
    e += __shfl_xor(e, 1, 64);                                          \
    e += __shfl_xor(e, 2, 64);                                          \
    e += __shfl_xor(e, 4, 64);                                          \
    e += __shfl_xor(e, 8, 64);                                          \
    const float tv = L[rb + tgt];                                       \
    const float ce = __logf(e) - tv;                                    \
    const float val = (tgt > 0) ? -ce : ce;                             \
    mined[(t) * 4 + r] = val;                                           \
  } while (0)

  int tile = (int)blockIdx.x * 4 + wid;
  float4 cA0, cA1, cB0, cB1;
  int4 tg0, tg1, tgN;

  LOAD_DATA(cA0, cA1, tile);
  tg0 = *reinterpret_cast<const int4*>(conf_targets + (size_t)tile * 4);
  {
    const int tB = tile + TOTAL_WAVES;   // always < NTILES4 (8188*24 layout)
    LOAD_DATA(cB0, cB1, tB);
    tg1 = *reinterpret_cast<const int4*>(conf_targets + (size_t)tB * 4);
  }

#pragma unroll 1
  for (int k = 0; k < KITERS; ++k) {
    // ---- body A ----
    STAGE(cA0, cA1);                      // waits on cA loads from 2 iters ago
    {
      int nt = tile + 2 * TOTAL_WAVES;
      nt = (nt < NTILES4) ? nt : tile;
      LOAD_DATA(cA0, cA1, nt);
      tgN = *reinterpret_cast<const int4*>(conf_targets + (size_t)nt * 4);
    }
    __builtin_amdgcn_sched_barrier(0);    // keep prefetch above compute
    COMPUTE(tile, tg0);
    tg0 = tg1; tg1 = tgN;
    tile += TOTAL_WAVES;

    // ---- body B ----
    STAGE(cB0, cB1);
    {
      int nt = tile + 2 * TOTAL_WAVES;
      nt = (nt < NTILES4) ? nt : tile;
      LOAD_DATA(cB0, cB1, nt);
      tgN = *reinterpret_cast<const int4*>(conf_targets + (size_t)nt * 4);
    }
    __builtin_amdgcn_sched_barrier(0);
    COMPUTE(tile, tg0);
    tg0 = tg1; tg1 = tgN;
    tile += TOTAL_WAVES;
  }
#undef LOAD_DATA
#undef STAGE
#undef COMPUTE
}

// One block per batch row (R16 structure; atomics on acc replaced by
// unconditional per-row partial writes -> no init kernel needed).
__global__ __launch_bounds__(1024) void mb_select(
    const float* __restrict__ mined, const float* __restrict__ loc_data,
    const float* __restrict__ loc_targets, float* __restrict__ partial,
    int* __restrict__ num_pos) {
  const int b = blockIdx.x;
  const float* __restrict__ row = mined + (size_t)b * NP;
  const int tid = threadIdx.x;
  const int wid = tid >> 6;
  const int lane = tid & 63;

  __shared__ int hist[16][256];
  __shared__ int total[256];
  __shared__ int suffix[256];
  __shared__ unsigned s_prefix;
  __shared__ int s_k;

  // ---- pre-pass: positives ----
  {
    int np = 0;
    float cp = 0.f, lv = 0.f;
    for (int q = tid; q < NP / 4; q += 1024) {
      const float4 v = reinterpret_cast<const float4*>(row)[q];
      const float vv[4] = {v.x, v.y, v.z, v.w};
#pragma unroll
      for (int j = 0; j < 4; ++j) {
        if (__float_as_uint(vv[j]) >> 31) {
          np++;
          cp += -vv[j];
          const size_t flat = (size_t)b * NP + 4 * q + j;
          lv += smooth_l1_4(
              *reinterpret_cast<const float4*>(loc_data + flat * 4),
              *reinterpret_cast<const float4*>(loc_targets + flat * 4));
        }
      }
    }
    __shared__ float rednp[16], redcp[16], redlv[16];
    float wnp = wave_reduce_sum((float)np);
    float wcp = wave_reduce_sum(cp);
    float wlv = wave_reduce_sum(lv);
    if (lane == 0) { rednp[wid] = wnp; redcp[wid] = wcp; redlv[wid] = wlv; }
    __syncthreads();
    if (tid == 0) {
      float tnp = 0.f, tcp = 0.f, tlv = 0.f;
#pragma unroll
      for (int i = 0; i < 16; ++i) { tnp += rednp[i]; tcp += redcp[i]; tlv += redlv[i]; }
      const int npi = (int)tnp;
      num_pos[b] = npi;
      partial[b * 4 + 0] = tlv;
      partial[b * 4 + 1] = tcp;
      int k = NEG_POS * npi;
      if (k > NP - 1) k = NP - 1;
      s_k = k;
      s_prefix = 0u;
    }
    __syncthreads();
  }

  // ---- radix select over masked values (sign-set -> 0.0) ----
  for (int shift = 24; shift >= 0; shift -= 8) {
    for (int i = tid; i < 16 * 256; i += 1024) ((int*)hist)[i] = 0;
    __syncthreads();
    const unsigned mask = (shift == 24) ? 0u : (0xFFFFFFFFu << (shift + 8));
    const unsigned pfx = s_prefix;
    const int kcur = s_k;

    for (int q = tid; q < NP / 4; q += 1024) {
      const float4 v = reinterpret_cast<const float4*>(row)[q];
      unsigned u;
      u = __float_as_uint(v.x); u = (u >> 31) ? 0u : u; if ((u & mask) == pfx) atomicAdd(&hist[wid][(u >> shift) & 255], 1);
      u = __float_as_uint(v.y); u = (u >> 31) ? 0u : u; if ((u & mask) == pfx) atomicAdd(&hist[wid][(u >> shift) & 255], 1);
      u = __float_as_uint(v.z); u = (u >> 31) ? 0u : u; if ((u & mask) == pfx) atomicAdd(&hist[wid][(u >> shift) & 255], 1);
      u = __float_as_uint(v.w); u = (u >> 31) ? 0u : u; if ((u & mask) == pfx) atomicAdd(&hist[wid][(u >> shift) & 255], 1);
    }
    __syncthreads();

    if (tid < 256) {
      int t = 0;
#pragma unroll
      for (int w = 0; w < 16; ++w) t += hist[w][tid];
      total[tid] = t;
    }
    __syncthreads();

    if (wid == 0) {
      const int t0_ = total[4 * lane + 0];
      const int t1_ = total[4 * lane + 1];
      const int t2_ = total[4 * lane + 2];
      const int t3_ = total[4 * lane + 3];
      const int s3 = t3_;
      const int s2 = t2_ + s3;
      const int s1 = t1_ + s2;
      const int s0 = t0_ + s1;
      int acc_ = s0;
#pragma unroll
      for (int off = 1; off < 64; off <<= 1) {
        const int o = __shfl_down(acc_, off, 64);
        if (lane + off < 64) acc_ += o;
      }
      const int excl = acc_ - s0;
      suffix[4 * lane + 0] = s0 + excl;
      suffix[4 * lane + 1] = s1 + excl;
      suffix[4 * lane + 2] = s2 + excl;
      suffix[4 * lane + 3] = s3 + excl;
    }
    __syncthreads();

    if (tid < 256) {
      const int cs = suffix[tid] - total[tid];
      if (kcur >= cs && kcur < cs + total[tid]) {
        s_prefix = pfx | ((unsigned)tid << shift);
        s_k = kcur - cs;
      }
    }
    __syncthreads();
  }

  const unsigned vbits = s_prefix;   // pivot bit pattern (masked domain)
  float sum = 0.f;
  for (int q = tid; q < NP / 4; q += 1024) {
    const float4 v = reinterpret_cast<const float4*>(row)[q];
    unsigned u;
    u = __float_as_uint(v.x); u = (u >> 31) ? 0u : u; if (u > vbits) sum += v.x;
    u = __float_as_uint(v.y); u = (u >> 31) ? 0u : u; if (u > vbits) sum += v.y;
    u = __float_as_uint(v.z); u = (u >> 31) ? 0u : u; if (u > vbits) sum += v.z;
    u = __float_as_uint(v.w); u = (u >> 31) ? 0u : u; if (u > vbits) sum += v.w;
  }

  __shared__ float wsum[16];
  float w = wave_reduce_sum(sum);
  if (lane == 0) wsum[wid] = w;
  __syncthreads();
  if (tid == 0) {
    float t = 0.f;
#pragma unroll
    for (int i = 0; i < 16; ++i) t += wsum[i];
    partial[b * 4 + 2] = t;
  }
}

__global__ void mb_finalize(const float* __restrict__ partial,
                            const int* __restrict__ num_pos,
                            float* __restrict__ out) {
  if (threadIdx.x == 0) {
    double s = 0.0;
    int tot = 0;
#pragma unroll
    for (int i = 0; i < NB; ++i) {
      s += (double)partial[i * 4 + 0] + (double)partial[i * 4 + 1] +
           (double)partial[i * 4 + 2];
      tot += num_pos[i];
    }
    const double n = (double)(tot > 0 ? tot : 1);
    out[0] = (float)(s / n);
  }
}

extern "C" void kernel_launch(void* const* d_in, const int* in_sizes, int n_in,
                              void* d_out, int out_size, void* d_ws, size_t ws_size,
                              hipStream_t stream) {
  const float* loc_data     = (const float*)d_in[0];
  const float* conf_data    = (const float*)d_in[1];
  const float* loc_targets  = (const float*)d_in[2];
  const int*   conf_targets = (const int*)d_in[3];
  float* out = (float*)d_out;

  float* mined   = (float*)d_ws;
  float* partial = (float*)((char*)d_ws + MINED_BYTES);
  int*   num_pos = (int*)((char*)d_ws + MINED_BYTES + 512);

  mb_main<<<MAIN_BLOCKS, 256, 0, stream>>>(conf_data, conf_targets, mined);

  mb_select<<<NB, 1024, 0, stream>>>(mined, loc_data, loc_targets, partial, num_pos);

  mb_finalize<<<1, 64, 0, stream>>>(partial, num_pos, out);
}

// Round 18
// 85.317 us; speedup vs baseline: 1.7734x; 1.1228x over previous
//
#include <hip/hip_runtime.h>
#include <cmath>
#include <cstdint>

#define NB 32
#define NP 24564
#define NC 81
#define NEG_POS 3

static constexpr size_t MINED_ELEMS = (size_t)NB * NP;             // 786,048
static constexpr size_t MINED_BYTES = MINED_ELEMS * sizeof(float); // 3,144,192

#define NTILES4 ((int)(MINED_ELEMS / 4))   // 196,512 = 8188 * 24 exactly
#define MAIN_BLOCKS 2047                   // 4 waves each -> 8188 waves
#define TOTAL_WAVES (MAIN_BLOCKS * 4)
#define KITERS 12                          // x2 bodies = 24 tiles per wave

// ws layout:
//   [0, MINED_BYTES)            float mined[NB*NP] (sign bit = positive row, |v| = ce)
//   [MINED_BYTES, +512)         float partial[NB][4] {loc, ce_pos, neg_sum, pad}
//   [MINED_BYTES+512, +4*NB)    int   num_pos[NB]

__device__ __forceinline__ float wave_reduce_sum(float v) {
#pragma unroll
  for (int off = 32; off > 0; off >>= 1) v += __shfl_down(v, off, 64);
  return v;
}

__device__ __forceinline__ float smooth_l1_4(float4 a, float4 t) {
  float acc = 0.f, d, ax;
  d = a.x - t.x; ax = fabsf(d); acc += (ax < 1.f) ? 0.5f * d * d : ax - 0.5f;
  d = a.y - t.y; ax = fabsf(d); acc += (ax < 1.f) ? 0.5f * d * d : ax - 0.5f;
  d = a.z - t.z; ax = fabsf(d); acc += (ax < 1.f) ? 0.5f * d * d : ax - 0.5f;
  d = a.w - t.w; ax = fabsf(d); acc += (ax < 1.f) ? 0.5f * d * d : ax - 0.5f;
  return acc;
}

// Branch-free CE kernel (R17, unchanged): depth-2 pipeline, targets rotate
// 3-deep; every wait is a rolling nonzero vmcnt.
__global__ __launch_bounds__(256, 8) void mb_main(
    const float* __restrict__ conf_data, const int* __restrict__ conf_targets,
    float* __restrict__ mined) {
  __shared__ float lds[4][332];   // 324 data + dump slot

  const int tid  = (int)threadIdx.x;
  const int wid  = tid >> 6, lane = tid & 63;
  const int r    = lane >> 4, il = lane & 15;
  float* __restrict__ L = lds[wid];

  const int l17   = (lane < 17) ? lane : 16;              // clamped src index
  const int ldst1 = (lane < 17) ? (256 + 4 * l17) : 328;  // dump for lanes>=17

#define LOAD_DATA(c0, c1, t)                                            \
  do {                                                                  \
    const float4* __restrict__ _s =                                     \
        reinterpret_cast<const float4*>(conf_data) + (size_t)(t) * 81;  \
    (c0) = _s[lane];                                                    \
    (c1) = _s[64 + l17];                                                \
  } while (0)

#define STAGE(c0, c1)                                  \
  do {                                                 \
    *reinterpret_cast<float4*>(&L[4 * lane]) = (c0);   \
    *reinterpret_cast<float4*>(&L[ldst1]) = (c1);      \
  } while (0)

#define COMPUTE(t, tg)                                                  \
  do {                                                                  \
    const int tgt = (r == 0) ? (tg).x : (r == 1) ? (tg).y               \
                  : (r == 2) ? (tg).z : (tg).w;                         \
    const int rb = 81 * r;                                              \
    float e = __expf(L[rb + il]) + __expf(L[rb + il + 16]) +            \
              __expf(L[rb + il + 32]) + __expf(L[rb + il + 48]) +       \
              __expf(L[rb + il + 64]);                                  \
    if (il == 0) e += __expf(L[rb + 80]);                               \
    e += __shfl_xor(e, 1, 64);                                          \
    e += __shfl_xor(e, 2, 64);                                          \
    e += __shfl_xor(e, 4, 64);                                          \
    e += __shfl_xor(e, 8, 64);                                          \
    const float tv = L[rb + tgt];                                       \
    const float ce = __logf(e) - tv;                                    \
    const float val = (tgt > 0) ? -ce : ce;                             \
    mined[(t) * 4 + r] = val;                                           \
  } while (0)

  int tile = (int)blockIdx.x * 4 + wid;
  float4 cA0, cA1, cB0, cB1;
  int4 tg0, tg1, tgN;

  LOAD_DATA(cA0, cA1, tile);
  tg0 = *reinterpret_cast<const int4*>(conf_targets + (size_t)tile * 4);
  {
    const int tB = tile + TOTAL_WAVES;   // always < NTILES4 (8188*24 layout)
    LOAD_DATA(cB0, cB1, tB);
    tg1 = *reinterpret_cast<const int4*>(conf_targets + (size_t)tB * 4);
  }

#pragma unroll 1
  for (int k = 0; k < KITERS; ++k) {
    // ---- body A ----
    STAGE(cA0, cA1);                      // waits on cA loads from 2 iters ago
    {
      int nt = tile + 2 * TOTAL_WAVES;
      nt = (nt < NTILES4) ? nt : tile;
      LOAD_DATA(cA0, cA1, nt);
      tgN = *reinterpret_cast<const int4*>(conf_targets + (size_t)nt * 4);
    }
    __builtin_amdgcn_sched_barrier(0);    // keep prefetch above compute
    COMPUTE(tile, tg0);
    tg0 = tg1; tg1 = tgN;
    tile += TOTAL_WAVES;

    // ---- body B ----
    STAGE(cB0, cB1);
    {
      int nt = tile + 2 * TOTAL_WAVES;
      nt = (nt < NTILES4) ? nt : tile;
      LOAD_DATA(cB0, cB1, nt);
      tgN = *reinterpret_cast<const int4*>(conf_targets + (size_t)nt * 4);
    }
    __builtin_amdgcn_sched_barrier(0);
    COMPUTE(tile, tg0);
    tg0 = tg1; tg1 = tgN;
    tile += TOTAL_WAVES;
  }
#undef LOAD_DATA
#undef STAGE
#undef COMPUTE
}

// One block per batch row. ONE change vs R17: positives pre-pass fused into
// radix pass 1 (the top-byte histogram doesn't depend on k; only the bin
// choice does, which happens after the np reduction). 4 sweeps total.
__global__ __launch_bounds__(1024) void mb_select(
    const float* __restrict__ mined, const float* __restrict__ loc_data,
    const float* __restrict__ loc_targets, float* __restrict__ partial,
    int* __restrict__ num_pos) {
  const int b = blockIdx.x;
  const float* __restrict__ row = mined + (size_t)b * NP;
  const int tid = threadIdx.x;
  const int wid = tid >> 6;
  const int lane = tid & 63;

  __shared__ int hist[16][256];
  __shared__ int total[256];
  __shared__ int suffix[256];
  __shared__ unsigned s_prefix;
  __shared__ int s_k;

  // ---- sweep 1: fused positives pre-pass + top-byte histogram ----
  for (int i = tid; i < 16 * 256; i += 1024) ((int*)hist)[i] = 0;
  __syncthreads();
  {
    int np = 0;
    float cp = 0.f, lv = 0.f;
    for (int q = tid; q < NP / 4; q += 1024) {
      const float4 v = reinterpret_cast<const float4*>(row)[q];
      const float vv[4] = {v.x, v.y, v.z, v.w};
#pragma unroll
      for (int j = 0; j < 4; ++j) {
        unsigned u = __float_as_uint(vv[j]);
        if (u >> 31) {
          np++;
          cp += -vv[j];
          const size_t flat = (size_t)b * NP + 4 * q + j;
          lv += smooth_l1_4(
              *reinterpret_cast<const float4*>(loc_data + flat * 4),
              *reinterpret_cast<const float4*>(loc_targets + flat * 4));
          u = 0u;
        }
        atomicAdd(&hist[wid][u >> 24], 1);
      }
    }
    __shared__ float rednp[16], redcp[16], redlv[16];
    float wnp = wave_reduce_sum((float)np);
    float wcp = wave_reduce_sum(cp);
    float wlv = wave_reduce_sum(lv);
    if (lane == 0) { rednp[wid] = wnp; redcp[wid] = wcp; redlv[wid] = wlv; }
    __syncthreads();
    if (tid == 0) {
      float tnp = 0.f, tcp = 0.f, tlv = 0.f;
#pragma unroll
      for (int i = 0; i < 16; ++i) { tnp += rednp[i]; tcp += redcp[i]; tlv += redlv[i]; }
      const int npi = (int)tnp;
      num_pos[b] = npi;
      partial[b * 4 + 0] = tlv;
      partial[b * 4 + 1] = tcp;
      int k = NEG_POS * npi;
      if (k > NP - 1) k = NP - 1;
      s_k = k;
      s_prefix = 0u;
    }
    __syncthreads();
  }

  // epilogue for a pass: totals -> wave-0 suffix scan -> choose bin
#define PASS_EPILOGUE(SHIFT)                                                  \
  do {                                                                        \
    if (tid < 256) {                                                          \
      int t = 0;                                                              \
      _Pragma("unroll")                                                       \
      for (int w = 0; w < 16; ++w) t += hist[w][tid];                         \
      total[tid] = t;                                                         \
    }                                                                         \
    __syncthreads();                                                          \
    if (wid == 0) {                                                           \
      const int t0_ = total[4 * lane + 0];                                    \
      const int t1_ = total[4 * lane + 1];                                    \
      const int t2_ = total[4 * lane + 2];                                    \
      const int t3_ = total[4 * lane + 3];                                    \
      const int s3 = t3_;                                                     \
      const int s2 = t2_ + s3;                                                \
      const int s1 = t1_ + s2;                                                \
      const int s0 = t0_ + s1;                                                \
      int acc_ = s0;                                                          \
      _Pragma("unroll")                                                       \
      for (int off = 1; off < 64; off <<= 1) {                                \
        const int o = __shfl_down(acc_, off, 64);                             \
        if (lane + off < 64) acc_ += o;                                       \
      }                                                                       \
      const int excl = acc_ - s0;                                             \
      suffix[4 * lane + 0] = s0 + excl;                                       \
      suffix[4 * lane + 1] = s1 + excl;                                       \
      suffix[4 * lane + 2] = s2 + excl;                                       \
      suffix[4 * lane + 3] = s3 + excl;                                       \
    }                                                                         \
    __syncthreads();                                                          \
    if (tid < 256) {                                                          \
      const int kcur = s_k;                                                   \
      const int cs = suffix[tid] - total[tid];                                \
      if (kcur >= cs && kcur < cs + total[tid]) {                             \
        s_prefix |= ((unsigned)tid << (SHIFT));                               \
        s_k = kcur - cs;                                                      \
      }                                                                       \
    }                                                                         \
    __syncthreads();                                                          \
  } while (0)

  PASS_EPILOGUE(24);

  // ---- sweeps 2..4 (shift 16, 8, 0) ----
  for (int shift = 16; shift >= 0; shift -= 8) {
    for (int i = tid; i < 16 * 256; i += 1024) ((int*)hist)[i] = 0;
    __syncthreads();
    const unsigned mask = 0xFFFFFFFFu << (shift + 8);
    const unsigned pfx = s_prefix;

    for (int q = tid; q < NP / 4; q += 1024) {
      const float4 v = reinterpret_cast<const float4*>(row)[q];
      unsigned u;
      u = __float_as_uint(v.x); u = (u >> 31) ? 0u : u; if ((u & mask) == pfx) atomicAdd(&hist[wid][(u >> shift) & 255], 1);
      u = __float_as_uint(v.y); u = (u >> 31) ? 0u : u; if ((u & mask) == pfx) atomicAdd(&hist[wid][(u >> shift) & 255], 1);
      u = __float_as_uint(v.z); u = (u >> 31) ? 0u : u; if ((u & mask) == pfx) atomicAdd(&hist[wid][(u >> shift) & 255], 1);
      u = __float_as_uint(v.w); u = (u >> 31) ? 0u : u; if ((u & mask) == pfx) atomicAdd(&hist[wid][(u >> shift) & 255], 1);
    }
    __syncthreads();

    if (shift == 16) PASS_EPILOGUE(16);
    else if (shift == 8) PASS_EPILOGUE(8);
    else PASS_EPILOGUE(0);
  }
#undef PASS_EPILOGUE

  // strictly-greater sum (L2-resident by now)
  const unsigned vbits = s_prefix;
  float sum = 0.f;
  for (int q = tid; q < NP / 4; q += 1024) {
    const float4 v = reinterpret_cast<const float4*>(row)[q];
    unsigned u;
    u = __float_as_uint(v.x); u = (u >> 31) ? 0u : u; if (u > vbits) sum += v.x;
    u = __float_as_uint(v.y); u = (u >> 31) ? 0u : u; if (u > vbits) sum += v.y;
    u = __float_as_uint(v.z); u = (u >> 31) ? 0u : u; if (u > vbits) sum += v.z;
    u = __float_as_uint(v.w); u = (u >> 31) ? 0u : u; if (u > vbits) sum += v.w;
  }

  __shared__ float wsum[16];
  float w = wave_reduce_sum(sum);
  if (lane == 0) wsum[wid] = w;
  __syncthreads();
  if (tid == 0) {
    float t = 0.f;
#pragma unroll
    for (int i = 0; i < 16; ++i) t += wsum[i];
    partial[b * 4 + 2] = t;
  }
}

__global__ void mb_finalize(const float* __restrict__ partial,
                            const int* __restrict__ num_pos,
                            float* __restrict__ out) {
  if (threadIdx.x == 0) {
    double s = 0.0;
    int tot = 0;
#pragma unroll
    for (int i = 0; i < NB; ++i) {
      s += (double)partial[i * 4 + 0] + (double)partial[i * 4 + 1] +
           (double)partial[i * 4 + 2];
      tot += num_pos[i];
    }
    const double n = (double)(tot > 0 ? tot : 1);
    out[0] = (float)(s / n);
  }
}

extern "C" void kernel_launch(void* const* d_in, const int* in_sizes, int n_in,
                              void* d_out, int out_size, void* d_ws, size_t ws_size,
                              hipStream_t stream) {
  const float* loc_data     = (const float*)d_in[0];
  const float* conf_data    = (const float*)d_in[1];
  const float* loc_targets  = (const float*)d_in[2];
  const int*   conf_targets = (const int*)d_in[3];
  float* out = (float*)d_out;

  float* mined   = (float*)d_ws;
  float* partial = (float*)((char*)d_ws + MINED_BYTES);
  int*   num_pos = (int*)((char*)d_ws + MINED_BYTES + 512);

  mb_main<<<MAIN_BLOCKS, 256, 0, stream>>>(conf_data, conf_targets, mined);

  mb_select<<<NB, 1024, 0, stream>>>(mined, loc_data, loc_targets, partial, num_pos);

  mb_finalize<<<1, 64, 0, stream>>>(partial, num_pos, out);
}